// Round 8
// baseline (236.047 us; speedup 1.0000x reference)
//
#include <hip/hip_runtime.h>
#include <hip/hip_bf16.h>

// ---------------------------------------------------------------------------
// GAT + 2 FC layers, MFMA + atomic-free CSR build (7 launches).
//   K0  : swizzle W_gat/W_fc1/W_fc2 (+WA att matrix) to MFMA B-frag order;
//         zero col_total
//   G1P1: fused [xp = x@W_gat MFMA + scores] and [coarse bucket histogram]
//   P2a : per-bucket scan of M over blocks + bucket bases; bucket_ptr/row_ptr[N]
//   P3  : scatter packed (src|dl<<17) into bucket segments (LDS rank)
//   P4  : per-bucket LDS hist -> row_ptr + csr_src + e_exp (bf16 softmax
//         numerators per edge*head, computed once here, lane-parallel)
//   K5  : per-dst aggregation: scalarized addressing (SGPR base + lane off),
//         bf16 e_exp weights, unroll x8 predicated -> z f32 + zb bf16
//   G2  : z1 = z@W_fc1+b1, z2 = z@W_fc2+b2 (bf16 MFMA, A from zb)
// ---------------------------------------------------------------------------

#define NBUCK  256
#define BSHIFT 9
#define BNODES 512
#define IPB    8192

typedef __attribute__((ext_vector_type(8))) short bf16x8;
typedef __attribute__((ext_vector_type(4))) float f32x4;

static __device__ __forceinline__ short f2bf(float f) {
    __hip_bfloat16 h = __float2bfloat16(f);
    return *reinterpret_cast<short*>(&h);
}

// ---------------- K0: weight swizzles + WA precompute + col_total zero -------
__global__ __launch_bounds__(256) void k0_swizzle(
    const float* __restrict__ W0, const float* __restrict__ W1,
    const float* __restrict__ W2, const float* __restrict__ att_s,
    const float* __restrict__ att_d, unsigned short* __restrict__ S0,
    unsigned short* __restrict__ S1, unsigned short* __restrict__ S2,
    unsigned short* __restrict__ Sa, int* __restrict__ col_total)
{
    const int t = blockIdx.x * 256 + threadIdx.x;
    if (t < NBUCK) col_total[t] = 0;
    if (t < 3 * 2048) {
        const int m = t >> 11;
        const int r = t & 2047;
        const int tile = r >> 6;          // cb*4 + ks
        const int l    = r & 63;
        const int ks   = tile & 3;
        const int cb   = tile >> 2;
        const int c    = cb * 16 + (l & 15);
        const int kb   = ks * 32 + (l >> 4) * 8;
        const float* W = (m == 0) ? W0 : (m == 1) ? W1 : W2;
        unsigned short* S = (m == 0) ? S0 : (m == 1) ? S1 : S2;
        unsigned short* dst = S + ((size_t)tile * 64 + l) * 8;
#pragma unroll
        for (int j = 0; j < 8; ++j)
            dst[j] = (unsigned short)f2bf(W[(kb + j) * 128 + c]);
    } else if (t < 3 * 2048 + 256) {
        const int r  = t - 3 * 2048;
        const int ks = r >> 6;
        const int l  = r & 63;
        const int hp = l & 15;
        const int h  = hp & 7;
        const float* av = (hp < 8) ? (att_s + h * 16) : (att_d + h * 16);
        unsigned short* dst = Sa + ((size_t)ks * 64 + l) * 8;
#pragma unroll
        for (int j = 0; j < 8; ++j) {
            const int k = ks * 32 + (l >> 4) * 8 + j;
            float acc = 0.f;
#pragma unroll
            for (int u = 0; u < 16; ++u)
                acc += W0[k * 128 + h * 16 + u] * av[u];
            dst[j] = (unsigned short)f2bf(acc);
        }
    }
}

// ---------------- G1P1: fused GEMM+scores | bucket histogram ----------------
__global__ __launch_bounds__(256) void g1p1(
    const float* __restrict__ x, const unsigned short* __restrict__ Wswz,
    const unsigned short* __restrict__ Sa, unsigned short* __restrict__ xpb,
    float* __restrict__ a_src, float* __restrict__ a_dst,
    const int* __restrict__ ei, int* __restrict__ M, int* __restrict__ col_total,
    int n, int E, int g1b, int nblk)
{
    if ((int)blockIdx.x < g1b) {
        const int wid  = __builtin_amdgcn_readfirstlane(threadIdx.x >> 6);
        const int lane = threadIdx.x & 63;
        const int lr   = lane & 15;
        const int kg   = lane >> 4;
        const int rowbase = blockIdx.x * 128 + wid * 32;

        bf16x8 afr[2][4];
#pragma unroll
        for (int rt = 0; rt < 2; ++rt) {
            int row = rowbase + rt * 16 + lr;
            row = (row < n) ? row : (n - 1);
            const float* rp = x + (size_t)row * 128 + kg * 8;
#pragma unroll
            for (int ks = 0; ks < 4; ++ks) {
                const float4 v0 = *reinterpret_cast<const float4*>(rp + ks * 32);
                const float4 v1 = *reinterpret_cast<const float4*>(rp + ks * 32 + 4);
                bf16x8 a;
                a[0] = f2bf(v0.x); a[1] = f2bf(v0.y); a[2] = f2bf(v0.z); a[3] = f2bf(v0.w);
                a[4] = f2bf(v1.x); a[5] = f2bf(v1.y); a[6] = f2bf(v1.z); a[7] = f2bf(v1.w);
                afr[rt][ks] = a;
            }
        }

        f32x4 acc[2][8] = {};
#pragma unroll
        for (int cb = 0; cb < 8; ++cb) {
            const unsigned short* bp = Wswz + ((size_t)(cb * 4) * 64 + lane) * 8;
            bf16x8 bfr[4];
#pragma unroll
            for (int ks = 0; ks < 4; ++ks)
                bfr[ks] = *reinterpret_cast<const bf16x8*>(bp + (size_t)ks * 512);
#pragma unroll
            for (int ks = 0; ks < 4; ++ks) {
                acc[0][cb] = __builtin_amdgcn_mfma_f32_16x16x32_bf16(afr[0][ks], bfr[ks], acc[0][cb], 0, 0, 0);
                acc[1][cb] = __builtin_amdgcn_mfma_f32_16x16x32_bf16(afr[1][ks], bfr[ks], acc[1][cb], 0, 0, 0);
            }
        }

        f32x4 accs[2] = {};
#pragma unroll
        for (int ks = 0; ks < 4; ++ks) {
            const bf16x8 bs = *reinterpret_cast<const bf16x8*>(Sa + ((size_t)ks * 64 + lane) * 8);
            accs[0] = __builtin_amdgcn_mfma_f32_16x16x32_bf16(afr[0][ks], bs, accs[0], 0, 0, 0);
            accs[1] = __builtin_amdgcn_mfma_f32_16x16x32_bf16(afr[1][ks], bs, accs[1], 0, 0, 0);
        }

#pragma unroll
        for (int rt = 0; rt < 2; ++rt) {
#pragma unroll
            for (int reg = 0; reg < 4; ++reg) {
                const int row = rowbase + rt * 16 + kg * 4 + reg;
                if (row < n) {
                    unsigned short* op = xpb + (size_t)row * 128 + lr;
#pragma unroll
                    for (int cb = 0; cb < 8; ++cb)
                        op[cb * 16] = (unsigned short)f2bf(acc[rt][cb][reg]);
                    if (lr < 8) a_src[row * 8 + lr] = accs[rt][reg];
                    else        a_dst[row * 8 + (lr - 8)] = accs[rt][reg];
                }
            }
        }
    } else {
        __shared__ int h[NBUCK];
        const int pb  = blockIdx.x - g1b;
        const int tid = threadIdx.x;
        for (int k = tid; k < NBUCK; k += 256) h[k] = 0;
        __syncthreads();

        const int tot = E + n;
        const int base = pb * IPB;
        const int lim = (base + IPB < tot) ? base + IPB : tot;
        for (int j = base + tid; j < lim; j += 256) {
            const int d = (j < E) ? ei[E + j] : (j - E);
            atomicAdd(&h[d >> BSHIFT], 1);
        }
        __syncthreads();
        for (int k = tid; k < NBUCK; k += 256) {
            M[(size_t)k * nblk + pb] = h[k];
            if (h[k]) atomicAdd(&col_total[k], h[k]);
        }
    }
}

// ---------------- P2a: bucket bases + per-bucket scan of M ----------------
__global__ __launch_bounds__(256) void p2a_colscan(
    int* __restrict__ M, const int* __restrict__ col_total,
    int* __restrict__ bucket_ptr, int* __restrict__ row_ptr, int nblk, int N)
{
    const int b    = blockIdx.x;
    const int tid  = threadIdx.x;
    const int lane = tid & 63;
    const int wid  = tid >> 6;
    __shared__ int wsum[4];
    __shared__ int sbase;

    const int v0 = col_total[tid];
    int ws0 = v0;
#pragma unroll
    for (int off = 1; off < 64; off <<= 1) {
        const int t = __shfl_up(ws0, off);
        if (lane >= off) ws0 += t;
    }
    if (lane == 63) wsum[wid] = ws0;
    __syncthreads();
    int woff0 = 0;
    for (int w2 = 0; w2 < wid; ++w2) woff0 += wsum[w2];
    const int excl0 = woff0 + ws0 - v0;
    if (tid == b) sbase = excl0;
    if (b == NBUCK - 1 && tid == NBUCK - 1) {
        bucket_ptr[NBUCK] = excl0 + v0;
        row_ptr[N] = excl0 + v0;
    }
    __syncthreads();
    const int base = sbase;
    if (tid == 0) bucket_ptr[b] = base;
    __syncthreads();

    int carry = base;
    for (int bb = 0; bb < nblk; bb += 256) {
        const int idx = bb + tid;
        const int v = (idx < nblk) ? M[(size_t)b * nblk + idx] : 0;
        int ws = v;
#pragma unroll
        for (int off = 1; off < 64; off <<= 1) {
            const int t = __shfl_up(ws, off);
            if (lane >= off) ws += t;
        }
        if (lane == 63) wsum[wid] = ws;
        __syncthreads();
        int woff = 0;
        for (int w2 = 0; w2 < wid; ++w2) woff += wsum[w2];
        const int alltot = wsum[0] + wsum[1] + wsum[2] + wsum[3];
        if (idx < nblk) M[(size_t)b * nblk + idx] = carry + woff + ws - v;
        carry += alltot;
        __syncthreads();
    }
}

// ---------------- P3: scatter packed (src | dl<<17) into bucket segments -----
__global__ __launch_bounds__(256) void p3_scatter(
    const int* __restrict__ ei, const int* __restrict__ M,
    int* __restrict__ pairs, int E, int N, int nblk)
{
    __shared__ int lcnt[NBUCK];
    const int tid = threadIdx.x;
    for (int k = tid; k < NBUCK; k += 256) lcnt[k] = 0;
    __syncthreads();

    const int tot = E + N;
    const int base = blockIdx.x * IPB;
    const int lim = (base + IPB < tot) ? base + IPB : tot;
    for (int j = base + tid; j < lim; j += 256) {
        int s, d;
        if (j < E) { s = ei[j]; d = ei[E + j]; }
        else       { s = j - E; d = s; }
        const int b = d >> BSHIFT;
        const int r = atomicAdd(&lcnt[b], 1);
        const int pos = M[(size_t)b * nblk + blockIdx.x] + r;
        pairs[pos] = s | ((d & (BNODES - 1)) << 17);
    }
}

// ---------------- P4: row_ptr + csr_src + e_exp (bf16 weights) ---------------
__global__ __launch_bounds__(256) void p4_finalize(
    const int* __restrict__ pairs, const int* __restrict__ bucket_ptr,
    const float* __restrict__ a_src, const float* __restrict__ a_dst,
    int* __restrict__ row_ptr, int* __restrict__ csr_src,
    unsigned short* __restrict__ e_exp, int N)
{
    const int b     = blockIdx.x;
    const int node0 = b << BSHIFT;
    const int beg   = bucket_ptr[b];
    const int end   = bucket_ptr[b + 1];
    const int tid   = threadIdx.x;
    const int lane  = tid & 63;
    const int wid   = tid >> 6;

    __shared__ int hist[BNODES];
    __shared__ int exc[BNODES];
    __shared__ int cnt2[BNODES];
    __shared__ int wsum[4];

    for (int k = tid; k < BNODES; k += 256) { hist[k] = 0; cnt2[k] = 0; }
    __syncthreads();

    for (int i = beg + tid; i < end; i += 256)
        atomicAdd(&hist[pairs[i] >> 17], 1);
    __syncthreads();

    const int a0 = hist[2 * tid];
    const int a1 = hist[2 * tid + 1];
    const int s  = a0 + a1;
    int ws = s;
#pragma unroll
    for (int off = 1; off < 64; off <<= 1) {
        const int t = __shfl_up(ws, off);
        if (lane >= off) ws += t;
    }
    if (lane == 63) wsum[wid] = ws;
    __syncthreads();
    int woff = 0;
    for (int w2 = 0; w2 < wid; ++w2) woff += wsum[w2];
    const int e0 = woff + ws - s;
    exc[2 * tid]     = e0;
    exc[2 * tid + 1] = e0 + a0;
    __syncthreads();

    for (int k = tid; k < BNODES; k += 256) {
        const int node = node0 + k;
        if (node < N) row_ptr[node] = beg + exc[k];
    }
    for (int i = beg + tid; i < end; i += 256) {
        const int v  = pairs[i];
        const int dl = v >> 17;
        const int sv = v & 0x1FFFF;
        const int r  = atomicAdd(&cnt2[dl], 1);
        const int pos = beg + exc[dl] + r;
        csr_src[pos] = sv;

        const float4 as0 = *reinterpret_cast<const float4*>(a_src + (size_t)sv * 8);
        const float4 as1 = *reinterpret_cast<const float4*>(a_src + (size_t)sv * 8 + 4);
        const float4 ad0 = *reinterpret_cast<const float4*>(a_dst + (size_t)(node0 + dl) * 8);
        const float4 ad1 = *reinterpret_cast<const float4*>(a_dst + (size_t)(node0 + dl) * 8 + 4);
        float vv[8];
        vv[0] = as0.x + ad0.x; vv[1] = as0.y + ad0.y;
        vv[2] = as0.z + ad0.z; vv[3] = as0.w + ad0.w;
        vv[4] = as1.x + ad1.x; vv[5] = as1.y + ad1.y;
        vv[6] = as1.z + ad1.z; vv[7] = as1.w + ad1.w;
        unsigned int pk[4];
#pragma unroll
        for (int q = 0; q < 4; ++q) {
            float u0 = vv[2 * q],     e0f;
            float u1 = vv[2 * q + 1], e1f;
            u0 = (u0 > 0.f) ? u0 : 0.2f * u0;
            u1 = (u1 > 0.f) ? u1 : 0.2f * u1;
            e0f = __expf(u0);
            e1f = __expf(u1);
            pk[q] = ((unsigned int)(unsigned short)f2bf(e1f) << 16) |
                    (unsigned int)(unsigned short)f2bf(e0f);
        }
        *reinterpret_cast<int4*>(e_exp + (size_t)pos * 8) =
            make_int4((int)pk[0], (int)pk[1], (int)pk[2], (int)pk[3]);
    }
}

// ---------------- K5: aggregation, scalarized addressing, unroll x8 ----------
__global__ __launch_bounds__(256) void k5_aggregate(
    const unsigned short* __restrict__ xpb, const unsigned short* __restrict__ e_exp,
    const int* __restrict__ row_ptr, const int* __restrict__ csr_src,
    const float* __restrict__ b_gat, float* __restrict__ z,
    unsigned int* __restrict__ zb, int n)
{
    const int wave = blockIdx.x * 4 + __builtin_amdgcn_readfirstlane(threadIdx.x >> 6);
    if (wave >= n) return;
    const int lane = threadIdx.x & 63;
    const int d = wave;
    const int beg = __builtin_amdgcn_readfirstlane(row_ptr[d]);
    const int end = __builtin_amdgcn_readfirstlane(row_ptr[d + 1]);
    const int h = lane >> 3;
    const int co = 2 * lane;

    float l0 = 0.f, l1 = 0.f;
    float ax0 = 0.f, ay0 = 0.f, ax1 = 0.f, ay1 = 0.f;

    for (int i = beg; i < end; i += 8) {
        int ss[8];
        float pw[8];
        unsigned int xv[8];
#pragma unroll
        for (int j = 0; j < 8; ++j) {
            const int idx = (i + j < end) ? (i + j) : (end - 1);
            ss[j] = __builtin_amdgcn_readfirstlane(csr_src[idx]);
            const unsigned int pu = (unsigned int)e_exp[(size_t)idx * 8 + h] << 16;
            const float p = __uint_as_float(pu);
            pw[j] = (i + j < end) ? p : 0.f;
        }
#pragma unroll
        for (int j = 0; j < 8; ++j)
            xv[j] = *reinterpret_cast<const unsigned int*>(xpb + (size_t)ss[j] * 128 + co);
#pragma unroll
        for (int j = 0; j < 8; ++j) {
            const float cx = __uint_as_float(xv[j] << 16);
            const float cy = __uint_as_float(xv[j] & 0xffff0000u);
            if (j & 1) {
                l1 += pw[j];
                ax1 = fmaf(pw[j], cx, ax1);
                ay1 = fmaf(pw[j], cy, ay1);
            } else {
                l0 += pw[j];
                ax0 = fmaf(pw[j], cx, ax0);
                ay0 = fmaf(pw[j], cy, ay0);
            }
        }
    }

    const float inv = 1.0f / (l0 + l1 + 1e-16f);
    const float2 bg = *reinterpret_cast<const float2*>(&b_gat[co]);
    float2 o;
    o.x = (ax0 + ax1) * inv + bg.x;
    o.y = (ay0 + ay1) * inv + bg.y;
    *reinterpret_cast<float2*>(&z[(size_t)d * 128 + co]) = o;
    const unsigned int pk = ((unsigned int)(unsigned short)f2bf(o.y) << 16) |
                            (unsigned int)(unsigned short)f2bf(o.x);
    zb[(size_t)d * 64 + lane] = pk;
}

// ---------------- G2: z1 = z@W1+b1, z2 = z@W2+b2 via MFMA (A from zb) -------
__global__ __launch_bounds__(256) void g2_mfma_fc(
    const unsigned int* __restrict__ zb,
    const unsigned short* __restrict__ S1, const unsigned short* __restrict__ S2,
    const float* __restrict__ b1, const float* __restrict__ b2,
    float* __restrict__ z1, float* __restrict__ z2, int n)
{
    const int wid  = __builtin_amdgcn_readfirstlane(threadIdx.x >> 6);
    const int lane = threadIdx.x & 63;
    const int lr   = lane & 15;
    const int kg   = lane >> 4;
    const int rowbase = blockIdx.x * 128 + wid * 32;

    bf16x8 afr[2][4];
#pragma unroll
    for (int rt = 0; rt < 2; ++rt) {
        int row = rowbase + rt * 16 + lr;
        row = (row < n) ? row : (n - 1);
        const unsigned short* rp = (const unsigned short*)(zb + (size_t)row * 64) + kg * 8;
#pragma unroll
        for (int ks = 0; ks < 4; ++ks)
            afr[rt][ks] = *reinterpret_cast<const bf16x8*>(rp + ks * 32);
    }

    f32x4 acc1[2][8] = {};
    f32x4 acc2[2][8] = {};
#pragma unroll
    for (int cb = 0; cb < 8; ++cb) {
        const unsigned short* bp1 = S1 + ((size_t)(cb * 4) * 64 + lane) * 8;
        const unsigned short* bp2 = S2 + ((size_t)(cb * 4) * 64 + lane) * 8;
        bf16x8 f1[4], f2v[4];
#pragma unroll
        for (int ks = 0; ks < 4; ++ks) {
            f1[ks]  = *reinterpret_cast<const bf16x8*>(bp1 + (size_t)ks * 512);
            f2v[ks] = *reinterpret_cast<const bf16x8*>(bp2 + (size_t)ks * 512);
        }
#pragma unroll
        for (int ks = 0; ks < 4; ++ks) {
            acc1[0][cb] = __builtin_amdgcn_mfma_f32_16x16x32_bf16(afr[0][ks], f1[ks],  acc1[0][cb], 0, 0, 0);
            acc1[1][cb] = __builtin_amdgcn_mfma_f32_16x16x32_bf16(afr[1][ks], f1[ks],  acc1[1][cb], 0, 0, 0);
            acc2[0][cb] = __builtin_amdgcn_mfma_f32_16x16x32_bf16(afr[0][ks], f2v[ks], acc2[0][cb], 0, 0, 0);
            acc2[1][cb] = __builtin_amdgcn_mfma_f32_16x16x32_bf16(afr[1][ks], f2v[ks], acc2[1][cb], 0, 0, 0);
        }
    }

    float bb1[8], bb2[8];
#pragma unroll
    for (int cb = 0; cb < 8; ++cb) { bb1[cb] = b1[cb * 16 + lr]; bb2[cb] = b2[cb * 16 + lr]; }

#pragma unroll
    for (int rt = 0; rt < 2; ++rt) {
#pragma unroll
        for (int reg = 0; reg < 4; ++reg) {
            const int row = rowbase + rt * 16 + kg * 4 + reg;
            if (row < n) {
                float* o1 = z1 + (size_t)row * 128 + lr;
                float* o2 = z2 + (size_t)row * 128 + lr;
#pragma unroll
                for (int cb = 0; cb < 8; ++cb) {
                    o1[cb * 16] = acc1[rt][cb][reg] + bb1[cb];
                    o2[cb * 16] = acc2[rt][cb][reg] + bb2[cb];
                }
            }
        }
    }
}

// ---------------------------------------------------------------------------
extern "C" void kernel_launch(void* const* d_in, const int* in_sizes, int n_in,
                              void* d_out, int out_size, void* d_ws, size_t ws_size,
                              hipStream_t stream)
{
    const float* x       = (const float*)d_in[0];
    const int*   ei      = (const int*)  d_in[1];
    const float* W_gat   = (const float*)d_in[2];
    const float* att_src = (const float*)d_in[3];
    const float* att_dst = (const float*)d_in[4];
    const float* b_gat   = (const float*)d_in[5];
    const float* W_fc1   = (const float*)d_in[6];
    const float* b_fc1   = (const float*)d_in[7];
    const float* W_fc2   = (const float*)d_in[8];
    const float* b_fc2   = (const float*)d_in[9];

    const int N = in_sizes[0] / 128;
    const int E = in_sizes[1] / 2;
    const int tot = E + N;
    const int nblk = (tot + IPB - 1) / IPB;
    const int nbuck_used = (N + BNODES - 1) >> BSHIFT;
    const int g1b = (N + 127) / 128;

    char* w = (char*)d_ws;
    unsigned short* xpb = (unsigned short*)w;  w += (size_t)N * 128 * 2;
    unsigned int* zb = (unsigned int*)w;       w += (size_t)N * 64 * 4;
    float* a_src  = (float*)w;  w += (size_t)N * 8 * 4;
    float* a_dst  = (float*)w;  w += (size_t)N * 8 * 4;
    int* row_ptr  = (int*)w;    w += (size_t)(N + 1) * 4;
    w = (char*)(((size_t)w + 15) & ~(size_t)15);
    unsigned short* S0 = (unsigned short*)w; w += 16384 * 2;
    unsigned short* S1 = (unsigned short*)w; w += 16384 * 2;
    unsigned short* S2 = (unsigned short*)w; w += 16384 * 2;
    unsigned short* Sa = (unsigned short*)w; w += 2048 * 2;
    int* M          = (int*)w;  w += (size_t)nblk * NBUCK * 4;
    int* col_total  = (int*)w;  w += NBUCK * 4;
    int* bucket_ptr = (int*)w;  w += (NBUCK + 1) * 4;
    w = (char*)(((size_t)w + 15) & ~(size_t)15);
    int* pairs    = (int*)w;    w += (size_t)tot * 4;
    int* csr_src  = (int*)w;    w += (size_t)tot * 4;
    w = (char*)(((size_t)w + 15) & ~(size_t)15);
    unsigned short* e_exp = (unsigned short*)w; w += (size_t)tot * 8 * 2;

    float* z  = (float*)d_out;
    float* z1 = z  + (size_t)N * 128;
    float* z2 = z1 + (size_t)N * 128;

    k0_swizzle<<<(3 * 2048 + 256 + 255) / 256, 256, 0, stream>>>(
        W_gat, W_fc1, W_fc2, att_src, att_dst, S0, S1, S2, Sa, col_total);

    g1p1<<<g1b + nblk, 256, 0, stream>>>(x, S0, Sa, xpb, a_src, a_dst,
                                         ei, M, col_total, N, E, g1b, nblk);

    p2a_colscan<<<NBUCK, 256, 0, stream>>>(M, col_total, bucket_ptr, row_ptr, nblk, N);
    p3_scatter<<<nblk, 256, 0, stream>>>(ei, M, pairs, E, N, nblk);
    p4_finalize<<<nbuck_used, 256, 0, stream>>>(pairs, bucket_ptr, a_src, a_dst,
                                                row_ptr, csr_src, e_exp, N);

    k5_aggregate<<<(N + 3) / 4, 256, 0, stream>>>(xpb, e_exp, row_ptr, csr_src,
                                                  b_gat, z, zb, N);

    g2_mfma_fc<<<(N + 127) / 128, 256, 0, stream>>>(zb, S1, S2, b_fc1, b_fc2, z1, z2, N);
}